// Round 9
// baseline (184.215 us; speedup 1.0000x reference)
//
#include <hip/hip_runtime.h>

typedef __attribute__((ext_vector_type(8))) short short8;
typedef __attribute__((ext_vector_type(4))) float f32x4;

// ---------- bf16 helpers (bit manip, round-to-nearest-even) ----------
__device__ __forceinline__ float bf2f(unsigned u16) {
    union { float f; unsigned u32; } v; v.u32 = u16 << 16; return v.f;
}
__device__ __forceinline__ unsigned short f2bf(float f) {
    union { float f; unsigned u32; } v; v.f = f;
    unsigned x = v.u32;
    x += ((x >> 16) & 1u) + 0x7FFFu;
    return (unsigned short)(x >> 16);
}

// ---------------------------------------------------------------------
// kprep: blocks [0,256): W[4][128][128] -> Wt[head][col][k] bf16.
//        blocks [256,512): W0[512][128] -> W0t[col][k] bf16.
//        blocks [512,514): b1[k][i] = W[k][i][:].a1[k], b2 likewise (f32).
// ---------------------------------------------------------------------
__global__ __launch_bounds__(256) void kprep(const float* __restrict__ W,
                                             const float* __restrict__ W0,
                                             const float* __restrict__ a1,
                                             const float* __restrict__ a2,
                                             unsigned short* __restrict__ Wt,
                                             unsigned short* __restrict__ W0t,
                                             float* __restrict__ b1,
                                             float* __restrict__ b2) {
    int b = blockIdx.x, t = threadIdx.x;
    if (b < 256) {
        int idx = b * 256 + t;
        int head = idx >> 14, rem = idx & 16383, k = rem >> 7, col = rem & 127;
        Wt[head * 16384 + col * 128 + k] = f2bf(W[idx]);
    } else if (b < 512) {
        int i2 = (b - 256) * 256 + t;
        int k = i2 >> 7, col = i2 & 127;
        W0t[col * 512 + k] = f2bf(W0[i2]);
    } else {
        int idx = (b - 512) * 256 + t;          // [0, 512)
        int k = idx >> 7, i = idx & 127;
        const float* wr = &W[k * 16384 + i * 128];
        const float* A1 = &a1[k * 128];
        const float* A2 = &a2[k * 128];
        float v1 = 0.f, v2 = 0.f;
        for (int c = 0; c < 128; ++c) { float wv = wr[c]; v1 += wv * A1[c]; v2 += wv * A2[c]; }
        b1[k * 128 + i] = v1;
        b2[k * 128 + i] = v2;
    }
}

// ---------------------------------------------------------------------
// kscore: per node (1 wave): hb = bf16(h); s1[n,k]=h.b1[k]; s2[n,k]=h.b2[k];
// g = softmax(h @ Wg). All from one read of h.
// ---------------------------------------------------------------------
__global__ __launch_bounds__(256) void kscore(const float* __restrict__ h,
                                              const float* __restrict__ Wg,
                                              const float* __restrict__ b1,
                                              const float* __restrict__ b2,
                                              unsigned* __restrict__ hb32,
                                              float* __restrict__ s1,
                                              float* __restrict__ s2,
                                              float* __restrict__ g,
                                              int N) {
    const int wave = threadIdx.x >> 6, lane = threadIdx.x & 63;
    const int n = blockIdx.x * 4 + wave;
    if (n >= N) return;

    float2 hv = *(const float2*)&h[(size_t)n * 128 + lane * 2];
    hb32[(size_t)n * 64 + lane] = (unsigned)f2bf(hv.x) | ((unsigned)f2bf(hv.y) << 16);

    float p[12];
    float4 wg0 = *(const float4*)&Wg[(lane * 2) * 4];
    float4 wg1 = *(const float4*)&Wg[(lane * 2 + 1) * 4];
    p[8]  = hv.x * wg0.x + hv.y * wg1.x;
    p[9]  = hv.x * wg0.y + hv.y * wg1.y;
    p[10] = hv.x * wg0.z + hv.y * wg1.z;
    p[11] = hv.x * wg0.w + hv.y * wg1.w;
    #pragma unroll
    for (int k = 0; k < 4; ++k) {
        float2 bv1 = *(const float2*)&b1[k * 128 + lane * 2];
        float2 bv2 = *(const float2*)&b2[k * 128 + lane * 2];
        p[k]     = hv.x * bv1.x + hv.y * bv1.y;
        p[4 + k] = hv.x * bv2.x + hv.y * bv2.y;
    }
    #pragma unroll
    for (int m = 32; m >= 1; m >>= 1) {
        #pragma unroll
        for (int i = 0; i < 12; ++i) p[i] += __shfl_xor(p[i], m, 64);
    }
    if (lane == 0) {
        *(float4*)&s1[n * 4] = make_float4(p[0], p[1], p[2], p[3]);
        *(float4*)&s2[n * 4] = make_float4(p[4], p[5], p[6], p[7]);
        float mx = fmaxf(fmaxf(p[8], p[9]), fmaxf(p[10], p[11]));
        float e0 = __expf(p[8] - mx), e1 = __expf(p[9] - mx);
        float e2 = __expf(p[10] - mx), e3 = __expf(p[11] - mx);
        float si = 1.f / (e0 + e1 + e2 + e3);
        *(float4*)&g[n * 4] = make_float4(e0 * si, e1 * si, e2 * si, e3 * si);
    }
}

// ---------------------------------------------------------------------
// k3_mix: one node per wave (4/block). Scores + softmax (per-head att ->
// LDS float4 per neighbor), then gather h_bf16[j] (256 B/row: 1 dword/lane)
// and accumulate mixed_k = sum_d att_k[d] * h[j_d] in f32.
// Store Mixed[n, k*128+c] bf16.   No barriers; wave-local LDS only.
// ---------------------------------------------------------------------
__global__ __launch_bounds__(256) void k3_mix(const int* __restrict__ idx,
                                              const unsigned* __restrict__ hb32,
                                              const float* __restrict__ s1,
                                              const float* __restrict__ s2,
                                              unsigned* __restrict__ Mx32,
                                              int N) {
    __shared__ float att4s[4][32][4];
    const int t = threadIdx.x, w = t >> 6, l = t & 63;
    const int d = l & 31, half = l >> 5;
    int n = blockIdx.x * 4 + w;
    const bool valid = (n < N);
    if (!valid) n = N - 1;

    // scores + softmax: lane (half,d) handles heads {2*half, 2*half+1}
    int j = idx[(size_t)n * 32 + d];
    float2 s2v = *(const float2*)&s2[(size_t)j * 4 + half * 2];
    const float* s1p = &s1[(size_t)n * 4];
    float e0 = s1p[half * 2] + s2v.x;
    float e1 = s1p[half * 2 + 1] + s2v.y;
    e0 = (e0 >= 0.f) ? e0 : 0.01f * e0;
    e1 = (e1 >= 0.f) ? e1 : 0.01f * e1;
    float m0 = e0, m1 = e1;
    #pragma unroll
    for (int mm = 16; mm >= 1; mm >>= 1) {
        m0 = fmaxf(m0, __shfl_xor(m0, mm, 32));
        m1 = fmaxf(m1, __shfl_xor(m1, mm, 32));
    }
    float p0 = __expf(e0 - m0), p1 = __expf(e1 - m1);
    float q0 = p0, q1 = p1;
    #pragma unroll
    for (int mm = 16; mm >= 1; mm >>= 1) {
        q0 += __shfl_xor(q0, mm, 32);
        q1 += __shfl_xor(q1, mm, 32);
    }
    *(float2*)&att4s[w][d][half * 2] = make_float2(p0 / q0, p1 / q1);

    // gather h rows, accumulate 4-head weighted sums; lane owns cols {2l,2l+1}
    float ac[4][2] = {};
    #pragma unroll
    for (int dd = 0; dd < 32; ++dd) {
        int jj = __shfl(j, dd, 64);
        unsigned hv = hb32[(size_t)jj * 64 + l];
        float h0 = bf2f(hv & 0xffffu);
        float h1 = bf2f(hv >> 16);
        float4 a4 = *(const float4*)&att4s[w][dd][0];
        ac[0][0] += a4.x * h0; ac[0][1] += a4.x * h1;
        ac[1][0] += a4.y * h0; ac[1][1] += a4.y * h1;
        ac[2][0] += a4.z * h0; ac[2][1] += a4.z * h1;
        ac[3][0] += a4.w * h0; ac[3][1] += a4.w * h1;
    }
    if (valid) {
        #pragma unroll
        for (int k = 0; k < 4; ++k) {
            unsigned pk = (unsigned)f2bf(ac[k][0]) | ((unsigned)f2bf(ac[k][1]) << 16);
            Mx32[(size_t)n * 256 + k * 64 + l] = pk;
        }
    }
}

// ---------------------------------------------------------------------
// k4_gemm v4: persistent grid-stride, 512 thr (8 waves), double-buffered
// 32-node tiles staged via global_load_lds with pre-swizzled source.
// Weights resident in registers for the whole kernel.
// phase 1: wave w -> head (w&3), row-group (w>>2): reads rows [rg*16,+16)
//   x head col-slice, writes EXACTLY the same region (same-wave ordering;
//   no cross-wave hazard -- the v3 race fix). bf1 = full head panel.
// phase 2: wave w -> col-group w of out = U @ W0t (bf2 resident).
// Per tile: ph1 | s_barrier(lgkm only; prefetch stays in flight) | ph2 |
// g-prefetch (before syncthreads, so vmcnt FIFO order keeps prefetch free) |
// __syncthreads | issue STAGE(t+2P).
// ---------------------------------------------------------------------
typedef const __attribute__((address_space(1))) char gbyte;
typedef __attribute__((address_space(3))) char lbyte;

__global__ __launch_bounds__(512, 1) void k4_gemm(const unsigned short* __restrict__ Mx,
                                                  const unsigned short* __restrict__ Wt,
                                                  const unsigned short* __restrict__ W0t,
                                                  const float* __restrict__ g,
                                                  float* __restrict__ out,
                                                  int N, int T) {
    __shared__ unsigned short U[2][32 * 512];   // 64 KB
    const int tid = threadIdx.x, w = tid >> 6, l = tid & 63;
    const int l15 = l & 15, lh = l >> 4;
    const int hd = w & 3, rg1 = w >> 2;         // phase-1 ownership
    const int P = gridDim.x;

    // resident B panels (loaded once per block)
    short8 bf1[4][8];                           // full head panel: 64 VGPR
    #pragma unroll
    for (int s = 0; s < 4; ++s)
        #pragma unroll
        for (int cg = 0; cg < 8; ++cg)
            bf1[s][cg] = *(const short8*)&Wt[(size_t)hd * 16384 +
                                             (size_t)(cg * 16 + l15) * 128 + s * 32 + lh * 8];
    short8 bf2[16];                             // col-group w of W0t: 64 VGPR
    #pragma unroll
    for (int ks = 0; ks < 16; ++ks)
        bf2[ks] = *(const short8*)&W0t[(size_t)(w * 16 + l15) * 512 + ks * 32 + lh * 8];

    const int t0 = blockIdx.x;

    auto STAGE = [&](int tile, int b) {
        const size_t n0 = (size_t)tile * 32;
        #pragma unroll
        for (int p = 0; p < 4; ++p) {
            int r = p * 8 + w;                       // one wave covers one 1024B row
            size_t n = n0 + r;
            if (n >= (size_t)N) n = N - 1;           // clamp (pad rows discarded later)
            // pre-swizzled global source; linear LDS dest (wave-uniform base)
            const char* src = (const char*)Mx + n * 1024 + ((l * 16) ^ ((r & 7) << 4));
            __builtin_amdgcn_global_load_lds((gbyte*)src, (lbyte*)&U[b][r * 512], 16, 0, 0);
        }
    };
    auto GLOAD = [&](int tile, float gv[4]) {
        #pragma unroll
        for (int r = 0; r < 4; ++r) {
            int n = tile * 32 + rg1 * 16 + lh * 4 + r;
            gv[r] = (tile < T && n < N) ? g[(size_t)n * 4 + hd] : 0.f;
        }
    };

    float gcur[4];
    GLOAD(t0, gcur);
    STAGE(t0, 0);
    __syncthreads();                                 // drains tile-0 stage
    if (t0 + P < T) STAGE(t0 + P, 1);

    int buf = 0;
    for (int t = t0; t < T; t += P, buf ^= 1) {
        const int n0 = t * 32;
        const char* Ubuf = (const char*)U[buf];

        // ---- phase 1: wave (hd,rg1): U = relu(Mixed@W_hd)*g_hd, in place ----
        {
            const int arow = rg1 * 16 + l15;
            short8 af[4];
            #pragma unroll
            for (int s = 0; s < 4; ++s) {
                int ab = arow * 1024 + hd * 256 + s * 64 + lh * 16;
                af[s] = *(const short8*)(Ubuf + (ab ^ ((arow & 7) << 4)));
            }
            f32x4 acc[8] = {};
            #pragma unroll
            for (int s = 0; s < 4; ++s)
                #pragma unroll
                for (int cg = 0; cg < 8; ++cg)
                    acc[cg] = __builtin_amdgcn_mfma_f32_16x16x32_bf16(af[s], bf1[s][cg], acc[cg], 0, 0, 0);
            #pragma unroll
            for (int cg = 0; cg < 8; ++cg)
                #pragma unroll
                for (int r = 0; r < 4; ++r) {
                    int row = rg1 * 16 + lh * 4 + r;
                    float v = fmaxf(acc[cg][r], 0.f) * gcur[r];
                    int ub = row * 1024 + hd * 256 + (cg * 16 + l15) * 2;
                    *(unsigned short*)((char*)U[buf] + (ub ^ ((row & 7) << 4))) = f2bf(v);
                }
        }

        // raw barrier: LDS visibility only — do NOT drain vmcnt (prefetch in flight)
        asm volatile("s_waitcnt lgkmcnt(0)" ::: "memory");
        __builtin_amdgcn_s_barrier();
        __builtin_amdgcn_sched_barrier(0);

        // ---- phase 2: wave w -> col-group w of out = U @ W0t ----
        #pragma unroll
        for (int rg = 0; rg < 2; ++rg) {
            const int arow = rg * 16 + l15;
            f32x4 oacc = {};
            #pragma unroll
            for (int ks = 0; ks < 16; ++ks) {
                int ab = arow * 1024 + ks * 64 + lh * 16;
                short8 afr = *(const short8*)(Ubuf + (ab ^ ((arow & 7) << 4)));
                oacc = __builtin_amdgcn_mfma_f32_16x16x32_bf16(afr, bf2[ks], oacc, 0, 0, 0);
            }
            #pragma unroll
            for (int r = 0; r < 4; ++r) {
                int n = n0 + rg * 16 + lh * 4 + r;
                if (n < N) out[(size_t)n * 128 + w * 16 + l15] = oacc[r];
            }
        }

        // g prefetch for next tile BEFORE the barrier/STAGE (vmcnt FIFO: waiting
        // on these later won't force the newer STAGE to drain)
        float gnext[4];
        GLOAD(t + P, gnext);

        __syncthreads();     // full drain: stage of U[buf^1] landed; all waves done with U[buf]
        if (t + 2 * P < T) STAGE(t + 2 * P, buf);
        #pragma unroll
        for (int r = 0; r < 4; ++r) gcur[r] = gnext[r];
    }
}

// ---------------------------------------------------------------------
extern "C" void kernel_launch(void* const* d_in, const int* in_sizes, int n_in,
                              void* d_out, int out_size, void* d_ws, size_t ws_size,
                              hipStream_t stream) {
    const float* h     = (const float*)d_in[0];
    const int*   neigh = (const int*)d_in[1];
    const float* W     = (const float*)d_in[2];
    const float* a1    = (const float*)d_in[3];
    const float* a2    = (const float*)d_in[4];
    const float* Wg    = (const float*)d_in[5];
    const float* W0    = (const float*)d_in[6];
    float* out = (float*)d_out;

    const int N = in_sizes[0] / 128;

    char* ws = (char*)d_ws;
    unsigned* hb32 = (unsigned*)ws;                                  // N*64 u32 (h bf16)
    unsigned* Mx32 = (unsigned*)(ws + (size_t)N * 256);              // N*256 u32 (Mixed bf16)
    float* s1 = (float*)(ws + (size_t)N * 256 + (size_t)N * 1024);   // N*4 f32
    float* s2 = s1 + (size_t)N * 4;
    float* g  = s2 + (size_t)N * 4;
    unsigned short* Wt  = (unsigned short*)(g + (size_t)N * 4);      // 128 KB
    unsigned short* W0t = Wt + 65536;                                // 128 KB
    float* b1 = (float*)(W0t + 65536);                               // 2 KB
    float* b2 = b1 + 512;                                            // 2 KB

    const int T = (N + 31) / 32;
    const int P = (T < 256) ? T : 256;

    kprep<<<dim3(514), dim3(256), 0, stream>>>(W, W0, a1, a2, Wt, W0t, b1, b2);
    kscore<<<dim3((N + 3) / 4), dim3(256), 0, stream>>>(h, Wg, b1, b2, hb32, s1, s2, g, N);
    k3_mix<<<dim3((N + 3) / 4), dim3(256), 0, stream>>>(neigh, hb32, s1, s2, Mx32, N);
    k4_gemm<<<dim3(P), dim3(512), 0, stream>>>((const unsigned short*)Mx32, Wt, W0t, g,
                                               out, N, T);
}

// Round 10
// 137.956 us; speedup vs baseline: 1.3353x; 1.3353x over previous
//
#include <hip/hip_runtime.h>

typedef __attribute__((ext_vector_type(8))) short short8;
typedef __attribute__((ext_vector_type(4))) float f32x4;

// ---------- bf16 helpers (bit manip, round-to-nearest-even) ----------
__device__ __forceinline__ float bf2f(unsigned u16) {
    union { float f; unsigned u32; } v; v.u32 = u16 << 16; return v.f;
}
__device__ __forceinline__ unsigned short f2bf(float f) {
    union { float f; unsigned u32; } v; v.f = f;
    unsigned x = v.u32;
    x += ((x >> 16) & 1u) + 0x7FFFu;
    return (unsigned short)(x >> 16);
}

// ---------------------------------------------------------------------
// kprep: blocks [0,256): W[4][128][128] -> Wt[head][col][k] bf16.
//        blocks [256,512): W0[512][128] -> W0t[col][k] bf16.
//        blocks [512,514): b1[k][i] = W[k][i][:].a1[k], b2 likewise (f32).
// ---------------------------------------------------------------------
__global__ __launch_bounds__(256) void kprep(const float* __restrict__ W,
                                             const float* __restrict__ W0,
                                             const float* __restrict__ a1,
                                             const float* __restrict__ a2,
                                             unsigned short* __restrict__ Wt,
                                             unsigned short* __restrict__ W0t,
                                             float* __restrict__ b1,
                                             float* __restrict__ b2) {
    int b = blockIdx.x, t = threadIdx.x;
    if (b < 256) {
        int idx = b * 256 + t;
        int head = idx >> 14, rem = idx & 16383, k = rem >> 7, col = rem & 127;
        Wt[head * 16384 + col * 128 + k] = f2bf(W[idx]);
    } else if (b < 512) {
        int i2 = (b - 256) * 256 + t;
        int k = i2 >> 7, col = i2 & 127;
        W0t[col * 512 + k] = f2bf(W0[i2]);
    } else {
        int idx = (b - 512) * 256 + t;          // [0, 512)
        int k = idx >> 7, i = idx & 127;
        const float* wr = &W[k * 16384 + i * 128];
        const float* A1 = &a1[k * 128];
        const float* A2 = &a2[k * 128];
        float v1 = 0.f, v2 = 0.f;
        for (int c = 0; c < 128; ++c) { float wv = wr[c]; v1 += wv * A1[c]; v2 += wv * A2[c]; }
        b1[k * 128 + i] = v1;
        b2[k * 128 + i] = v2;
    }
}

// ---------------------------------------------------------------------
// kscore: per node (1 wave): hb = bf16(h); s1[n,k]=h.b1[k]; s2[n,k]=h.b2[k];
// g = softmax(h @ Wg). All from one read of h.
// ---------------------------------------------------------------------
__global__ __launch_bounds__(256) void kscore(const float* __restrict__ h,
                                              const float* __restrict__ Wg,
                                              const float* __restrict__ b1,
                                              const float* __restrict__ b2,
                                              unsigned* __restrict__ hb32,
                                              float* __restrict__ s1,
                                              float* __restrict__ s2,
                                              float* __restrict__ g,
                                              int N) {
    const int wave = threadIdx.x >> 6, lane = threadIdx.x & 63;
    const int n = blockIdx.x * 4 + wave;
    if (n >= N) return;

    float2 hv = *(const float2*)&h[(size_t)n * 128 + lane * 2];
    hb32[(size_t)n * 64 + lane] = (unsigned)f2bf(hv.x) | ((unsigned)f2bf(hv.y) << 16);

    float p[12];
    float4 wg0 = *(const float4*)&Wg[(lane * 2) * 4];
    float4 wg1 = *(const float4*)&Wg[(lane * 2 + 1) * 4];
    p[8]  = hv.x * wg0.x + hv.y * wg1.x;
    p[9]  = hv.x * wg0.y + hv.y * wg1.y;
    p[10] = hv.x * wg0.z + hv.y * wg1.z;
    p[11] = hv.x * wg0.w + hv.y * wg1.w;
    #pragma unroll
    for (int k = 0; k < 4; ++k) {
        float2 bv1 = *(const float2*)&b1[k * 128 + lane * 2];
        float2 bv2 = *(const float2*)&b2[k * 128 + lane * 2];
        p[k]     = hv.x * bv1.x + hv.y * bv1.y;
        p[4 + k] = hv.x * bv2.x + hv.y * bv2.y;
    }
    #pragma unroll
    for (int m = 32; m >= 1; m >>= 1) {
        #pragma unroll
        for (int i = 0; i < 12; ++i) p[i] += __shfl_xor(p[i], m, 64);
    }
    if (lane == 0) {
        *(float4*)&s1[n * 4] = make_float4(p[0], p[1], p[2], p[3]);
        *(float4*)&s2[n * 4] = make_float4(p[4], p[5], p[6], p[7]);
        float mx = fmaxf(fmaxf(p[8], p[9]), fmaxf(p[10], p[11]));
        float e0 = __expf(p[8] - mx), e1 = __expf(p[9] - mx);
        float e2 = __expf(p[10] - mx), e3 = __expf(p[11] - mx);
        float si = 1.f / (e0 + e1 + e2 + e3);
        *(float4*)&g[n * 4] = make_float4(e0 * si, e1 * si, e2 * si, e3 * si);
    }
}

// ---------------------------------------------------------------------
// k3_mix: one node per wave (4/block). Scores + softmax (per-head att ->
// LDS float4 per neighbor), then gather h_bf16[j] (256 B/row: 1 dword/lane)
// and accumulate mixed_k = sum_d att_k[d] * h[j_d] in f32.
// Store Mixed[n, k*128+c] bf16.   No barriers; wave-local LDS only.
// ---------------------------------------------------------------------
__global__ __launch_bounds__(256) void k3_mix(const int* __restrict__ idx,
                                              const unsigned* __restrict__ hb32,
                                              const float* __restrict__ s1,
                                              const float* __restrict__ s2,
                                              unsigned* __restrict__ Mx32,
                                              int N) {
    __shared__ float att4s[4][32][4];
    const int t = threadIdx.x, w = t >> 6, l = t & 63;
    const int d = l & 31, half = l >> 5;
    int n = blockIdx.x * 4 + w;
    const bool valid = (n < N);
    if (!valid) n = N - 1;

    // scores + softmax: lane (half,d) handles heads {2*half, 2*half+1}
    int j = idx[(size_t)n * 32 + d];
    float2 s2v = *(const float2*)&s2[(size_t)j * 4 + half * 2];
    const float* s1p = &s1[(size_t)n * 4];
    float e0 = s1p[half * 2] + s2v.x;
    float e1 = s1p[half * 2 + 1] + s2v.y;
    e0 = (e0 >= 0.f) ? e0 : 0.01f * e0;
    e1 = (e1 >= 0.f) ? e1 : 0.01f * e1;
    float m0 = e0, m1 = e1;
    #pragma unroll
    for (int mm = 16; mm >= 1; mm >>= 1) {
        m0 = fmaxf(m0, __shfl_xor(m0, mm, 32));
        m1 = fmaxf(m1, __shfl_xor(m1, mm, 32));
    }
    float p0 = __expf(e0 - m0), p1 = __expf(e1 - m1);
    float q0 = p0, q1 = p1;
    #pragma unroll
    for (int mm = 16; mm >= 1; mm >>= 1) {
        q0 += __shfl_xor(q0, mm, 32);
        q1 += __shfl_xor(q1, mm, 32);
    }
    *(float2*)&att4s[w][d][half * 2] = make_float2(p0 / q0, p1 / q1);

    // gather h rows, accumulate 4-head weighted sums; lane owns cols {2l,2l+1}
    float ac[4][2] = {};
    #pragma unroll
    for (int dd = 0; dd < 32; ++dd) {
        int jj = __shfl(j, dd, 64);
        unsigned hv = hb32[(size_t)jj * 64 + l];
        float h0 = bf2f(hv & 0xffffu);
        float h1 = bf2f(hv >> 16);
        float4 a4 = *(const float4*)&att4s[w][dd][0];
        ac[0][0] += a4.x * h0; ac[0][1] += a4.x * h1;
        ac[1][0] += a4.y * h0; ac[1][1] += a4.y * h1;
        ac[2][0] += a4.z * h0; ac[2][1] += a4.z * h1;
        ac[3][0] += a4.w * h0; ac[3][1] += a4.w * h1;
    }
    if (valid) {
        #pragma unroll
        for (int k = 0; k < 4; ++k) {
            unsigned pk = (unsigned)f2bf(ac[k][0]) | ((unsigned)f2bf(ac[k][1]) << 16);
            Mx32[(size_t)n * 256 + k * 64 + l] = pk;
        }
    }
}

// ---------------------------------------------------------------------
// k4_gemm v5: persistent, 512 thr (8 waves), SPILL-FREE register budget.
//   bf1 (ph1): wave -> head (w&3), col-half (w>>2): 16 frags = 64 VGPR
//   bf2 (ph2): wave -> col-group w of W0t:          16 frags = 64 VGPR
// LDS: Uin[2] (dbuf, staged via global_load_lds w/ pre-swizzled src),
//      Uout (ph1 output — separate buffer => read-set∩write-set=∅, no race),
//      gld[2] (gate rows staged via global_load_lds).
// Per tile: ph1(Uin[buf],g->Uout) | sync | STAGE(t+2P->Uin[buf]) |
//           ph2(Uout->out) | sync.   All barriers are plain __syncthreads.
// ---------------------------------------------------------------------
typedef const __attribute__((address_space(1))) char gbyte;
typedef __attribute__((address_space(3))) char lbyte;

__global__ __launch_bounds__(512, 1) void k4_gemm(const unsigned short* __restrict__ Mx,
                                                  const unsigned short* __restrict__ Wt,
                                                  const unsigned short* __restrict__ W0t,
                                                  const float* __restrict__ g,
                                                  float* __restrict__ out,
                                                  int N, int T) {
    __shared__ unsigned short Uin[2][32 * 512];   // 64 KB
    __shared__ unsigned short Uout[32 * 512];     // 32 KB
    __shared__ float gld[2][128];                 // 1 KB
    const int tid = threadIdx.x, w = tid >> 6, l = tid & 63;
    const int l15 = l & 15, lh = l >> 4;
    const int hd = w & 3, ch = w >> 2;
    const int P = gridDim.x;

    // resident B panels: 64 + 64 VGPR (fits; no spill)
    short8 bf1[4][4];
    #pragma unroll
    for (int s = 0; s < 4; ++s)
        #pragma unroll
        for (int c = 0; c < 4; ++c)
            bf1[s][c] = *(const short8*)&Wt[(size_t)hd * 16384 +
                                            (size_t)((ch * 4 + c) * 16 + l15) * 128 + s * 32 + lh * 8];
    short8 bf2[16];
    #pragma unroll
    for (int ks = 0; ks < 16; ++ks)
        bf2[ks] = *(const short8*)&W0t[(size_t)(w * 16 + l15) * 512 + ks * 32 + lh * 8];

    const int t0 = blockIdx.x;

    auto STAGE = [&](int tile, int b) {
        const size_t n0 = (size_t)tile * 32;
        if (w == 0 && l < 32) {                      // gate rows: 32 x 16 B
            size_t n = n0 + l; if (n >= (size_t)N) n = N - 1;
            __builtin_amdgcn_global_load_lds((gbyte*)((const char*)g + n * 16),
                                             (lbyte*)&gld[b][0], 16, 0, 0);
        }
        #pragma unroll
        for (int p = 0; p < 4; ++p) {
            int r = p * 8 + w;                       // one wave covers one 1024B row
            size_t n = n0 + r;
            if (n >= (size_t)N) n = N - 1;           // clamp (pad rows discarded later)
            // pre-swizzled global source; linear LDS dest (wave-uniform base)
            const char* src = (const char*)Mx + n * 1024 + ((l * 16) ^ ((r & 7) << 4));
            __builtin_amdgcn_global_load_lds((gbyte*)src, (lbyte*)&Uin[b][r * 512], 16, 0, 0);
        }
    };

    STAGE(t0, 0);
    __syncthreads();                                 // tile-0 staged
    if (t0 + P < T) STAGE(t0 + P, 1);

    int buf = 0;
    for (int t = t0; t < T; t += P, buf ^= 1) {
        const int n0 = t * 32;

        // ---- phase 1: Uout = relu(Uin[buf] @ W_hd) * g, cols (hd,ch) ----
        const char* Uibuf = (const char*)Uin[buf];
        #pragma unroll
        for (int rg = 0; rg < 2; ++rg) {
            const int arow = rg * 16 + l15;
            short8 af[4];
            #pragma unroll
            for (int s = 0; s < 4; ++s) {
                int ab = arow * 1024 + hd * 256 + s * 64 + lh * 16;
                af[s] = *(const short8*)(Uibuf + (ab ^ ((arow & 7) << 4)));
            }
            f32x4 acc[4] = {};
            #pragma unroll
            for (int s = 0; s < 4; ++s)
                #pragma unroll
                for (int c = 0; c < 4; ++c)
                    acc[c] = __builtin_amdgcn_mfma_f32_16x16x32_bf16(af[s], bf1[s][c], acc[c], 0, 0, 0);
            #pragma unroll
            for (int c = 0; c < 4; ++c) {
                const int col = hd * 128 + (ch * 4 + c) * 16 + l15;
                #pragma unroll
                for (int r = 0; r < 4; ++r) {
                    int row = rg * 16 + lh * 4 + r;
                    float v = fmaxf(acc[c][r], 0.f) * gld[buf][row * 4 + hd];
                    int ub = row * 1024 + col * 2;
                    *(unsigned short*)((char*)Uout + (ub ^ ((row & 7) << 4))) = f2bf(v);
                }
            }
        }

        __syncthreads();     // Uout visible; Uin[buf] free; (drains in-flight stage)

        if (t + 2 * P < T) STAGE(t + 2 * P, buf);   // overlaps phase 2

        // ---- phase 2: out = Uout @ W0t; wave w -> col-group w ----
        const char* Uob = (const char*)Uout;
        #pragma unroll
        for (int rg = 0; rg < 2; ++rg) {
            const int arow = rg * 16 + l15;
            f32x4 oacc = {};
            #pragma unroll
            for (int ks = 0; ks < 16; ++ks) {
                int ab = arow * 1024 + ks * 64 + lh * 16;
                short8 afr = *(const short8*)(Uob + (ab ^ ((arow & 7) << 4)));
                oacc = __builtin_amdgcn_mfma_f32_16x16x32_bf16(afr, bf2[ks], oacc, 0, 0, 0);
            }
            #pragma unroll
            for (int r = 0; r < 4; ++r) {
                int n = n0 + rg * 16 + lh * 4 + r;
                if (n < N) out[(size_t)n * 128 + w * 16 + l15] = oacc[r];
            }
        }

        __syncthreads();     // all ph2 reads of Uout done; stage(t+2P) landed
    }
}

// ---------------------------------------------------------------------
extern "C" void kernel_launch(void* const* d_in, const int* in_sizes, int n_in,
                              void* d_out, int out_size, void* d_ws, size_t ws_size,
                              hipStream_t stream) {
    const float* h     = (const float*)d_in[0];
    const int*   neigh = (const int*)d_in[1];
    const float* W     = (const float*)d_in[2];
    const float* a1    = (const float*)d_in[3];
    const float* a2    = (const float*)d_in[4];
    const float* Wg    = (const float*)d_in[5];
    const float* W0    = (const float*)d_in[6];
    float* out = (float*)d_out;

    const int N = in_sizes[0] / 128;

    char* ws = (char*)d_ws;
    unsigned* hb32 = (unsigned*)ws;                                  // N*64 u32 (h bf16)
    unsigned* Mx32 = (unsigned*)(ws + (size_t)N * 256);              // N*256 u32 (Mixed bf16)
    float* s1 = (float*)(ws + (size_t)N * 256 + (size_t)N * 1024);   // N*4 f32
    float* s2 = s1 + (size_t)N * 4;
    float* g  = s2 + (size_t)N * 4;
    unsigned short* Wt  = (unsigned short*)(g + (size_t)N * 4);      // 128 KB
    unsigned short* W0t = Wt + 65536;                                // 128 KB
    float* b1 = (float*)(W0t + 65536);                               // 2 KB
    float* b2 = b1 + 512;                                            // 2 KB

    const int T = (N + 31) / 32;
    const int P = (T < 256) ? T : 256;

    kprep<<<dim3(514), dim3(256), 0, stream>>>(W, W0, a1, a2, Wt, W0t, b1, b2);
    kscore<<<dim3((N + 3) / 4), dim3(256), 0, stream>>>(h, Wg, b1, b2, hb32, s1, s2, g, N);
    k3_mix<<<dim3((N + 3) / 4), dim3(256), 0, stream>>>(neigh, hb32, s1, s2, Mx32, N);
    k4_gemm<<<dim3(P), dim3(512), 0, stream>>>((const unsigned short*)Mx32, Wt, W0t, g,
                                               out, N, T);
}